// Round 7
// baseline (705.309 us; speedup 1.0000x reference)
//
#include <hip/hip_runtime.h>
#include <hip/hip_bf16.h>
#include <cstdint>
#include <cstddef>

#define NN 50000
#define NE 800000

typedef __bf16 bf16x8 __attribute__((ext_vector_type(8)));
typedef float  f32x4  __attribute__((ext_vector_type(4)));

// Pre-split, pre-transposed weights (hi/lo bf16 planes).
// W1t: [n][k] n<64,k<256 ; W2t: [n][k] n<128,k<64 ; Wd1t: [n][k] n<64,k<128.
__device__ __bf16 g_w1h[2][64 * 256];
__device__ __bf16 g_w1l[2][64 * 256];
__device__ __bf16 g_w2h[2][128 * 64];
__device__ __bf16 g_w2l[2][128 * 64];
__device__ __bf16 g_wd1h[64 * 128];
__device__ __bf16 g_wd1l[64 * 128];

__device__ __forceinline__ void split1(float v, __bf16& h, __bf16& l) {
    h = (__bf16)v;
    l = (__bf16)(v - (float)h);
}

// ---------------------------------------------------------------------------
// pre_kernel: blocks [0,224) split weights; blocks [224,224+3125) histogram
// ---------------------------------------------------------------------------
__global__ __launch_bounds__(256) void pre_kernel(
    const float* __restrict__ W1a, const float* __restrict__ W2a,
    const float* __restrict__ W1b, const float* __restrict__ W2b,
    const float* __restrict__ Wd1,
    const int* __restrict__ rcv, uint32_t* __restrict__ hist)
{
    const int b = blockIdx.x, t = threadIdx.x;
    if (b < 224) {
        int tid = b * 256 + t;
        if (tid < 16384) {                 // W1a [256][64] -> [64][256]
            int k = tid >> 6, n = tid & 63;
            __bf16 h, l; split1(W1a[tid], h, l);
            g_w1h[0][n * 256 + k] = h; g_w1l[0][n * 256 + k] = l;
        } else if (tid < 24576) {          // W2a [64][128] -> [128][64]
            int i = tid - 16384; int k = i >> 7, n = i & 127;
            __bf16 h, l; split1(W2a[i], h, l);
            g_w2h[0][n * 64 + k] = h; g_w2l[0][n * 64 + k] = l;
        } else if (tid < 40960) {          // W1b
            int i = tid - 24576; int k = i >> 6, n = i & 63;
            __bf16 h, l; split1(W1b[i], h, l);
            g_w1h[1][n * 256 + k] = h; g_w1l[1][n * 256 + k] = l;
        } else if (tid < 49152) {          // W2b
            int i = tid - 40960; int k = i >> 7, n = i & 127;
            __bf16 h, l; split1(W2b[i], h, l);
            g_w2h[1][n * 64 + k] = h; g_w2l[1][n * 64 + k] = l;
        } else if (tid < 57344) {          // Wd1 [128][64] -> [64][128]
            int i = tid - 49152; int k = i >> 6, n = i & 63;
            __bf16 h, l; split1(Wd1[i], h, l);
            g_wd1h[n * 128 + k] = h; g_wd1l[n * 128 + k] = l;
        }
    } else {
        int e = (b - 224) * 256 + t;
        if (e < NE) atomicAdd(hist + rcv[e], 1u);
    }
}

// ---------------------------------------------------------------------------
// counting-sort scan (exact counts)
// ---------------------------------------------------------------------------
__global__ void scan1_kernel(const uint32_t* __restrict__ hist,
                             uint32_t* __restrict__ pre, uint32_t* __restrict__ bsum) {
    __shared__ uint32_t s[256];
    int t = threadIdx.x;
    int i = blockIdx.x * 256 + t;
    uint32_t v = (i < NN) ? hist[i] : 0u;
    s[t] = v; __syncthreads();
    #pragma unroll
    for (int off = 1; off < 256; off <<= 1) {
        uint32_t tv = (t >= off) ? s[t - off] : 0u;
        __syncthreads();
        s[t] += tv; __syncthreads();
    }
    if (i < NN) pre[i] = s[t] - v;
    if (t == 255) bsum[blockIdx.x] = s[255];
}

__global__ void scan23_kernel(const uint32_t* __restrict__ pre,
                              const uint32_t* __restrict__ bsum,
                              uint32_t* __restrict__ row_off) {
    __shared__ uint32_t s[256];
    const int b = blockIdx.x, t = threadIdx.x;
    uint32_t v = (t < b) ? bsum[t] : 0u;     // b <= 195 < 256
    s[t] = v; __syncthreads();
    #pragma unroll
    for (int off = 128; off > 0; off >>= 1) {
        if (t < off) s[t] += s[t + off];
        __syncthreads();
    }
    const uint32_t base = s[0];
    int i = b * 256 + t;
    if (i < NN) row_off[i] = pre[i] + base;
    if (i == 0) row_off[NN] = NE;
}

// ---------------------------------------------------------------------------
// node_w1_body: per-node half-products of GEMM1.
//   hrp[n] = src[n] @ W1_top + b1 ; hsp[n] = src[n] @ W1_bot
// mean-mode (row_off != null): scale src by 1/cnt (cnt = row_off diff).
// No seg rezero (edge_acc overwrites seg with plain stores).
// ---------------------------------------------------------------------------
__device__ __forceinline__ void node_w1_body(
    const float* __restrict__ src, const uint32_t* __restrict__ row_off,
    const float* __restrict__ b1,
    float* __restrict__ hrp, float* __restrict__ hsp, int layer, int blk)
{
    __shared__ __align__(16) __bf16 sAh[64 * 136];
    __shared__ __align__(16) __bf16 sAl[64 * 136];
    const int t = threadIdx.x;
    const int w = t >> 6, lane = t & 63, quad = lane >> 4, l16 = lane & 15;
    const int node0 = blk * 64;

    {
        const int r = t >> 2, kq = (t & 3) * 32;
        const int node = node0 + r;
        f32x4 v[8];
        if (node < NN) {
            const float* p = src + (size_t)node * 128 + kq;
            #pragma unroll
            for (int i = 0; i < 8; ++i) v[i] = *(const f32x4*)(p + 4 * i);
            if (row_off) {
                uint32_t c = row_off[node + 1] - row_off[node];
                float inv = (c > 0u) ? 1.0f / (float)c : 0.f;
                #pragma unroll
                for (int i = 0; i < 8; ++i) v[i] = v[i] * inv;
            }
        } else {
            #pragma unroll
            for (int i = 0; i < 8; ++i) v[i] = (f32x4){0.f, 0.f, 0.f, 0.f};
        }
        bf16x8 hb[4], lb[4];
        #pragma unroll
        for (int i = 0; i < 8; ++i) {
            #pragma unroll
            for (int j = 0; j < 4; ++j) {
                __bf16 h, l; split1(v[i][j], h, l);
                hb[i >> 1][(i & 1) * 4 + j] = h;
                lb[i >> 1][(i & 1) * 4 + j] = l;
            }
        }
        __bf16* dh = sAh + r * 136 + kq;
        __bf16* dl = sAl + r * 136 + kq;
        #pragma unroll
        for (int i = 0; i < 4; ++i) {
            *(bf16x8*)(dh + 8 * i) = hb[i];
            *(bf16x8*)(dl + 8 * i) = lb[i];
        }
    }
    __syncthreads();

    const int n = 16 * w + l16;
    const __bf16* w1hp = g_w1h[layer] + n * 256;
    const __bf16* w1lp = g_w1l[layer] + n * 256;
    f32x4 acc[4][2] = {};
    #pragma unroll
    for (int kq = 0; kq < 4; ++kq) {
        const int k0 = kq * 32 + quad * 8;
        bf16x8 bh0 = *(const bf16x8*)(w1hp + k0);
        bf16x8 bl0 = *(const bf16x8*)(w1lp + k0);
        bf16x8 bh1 = *(const bf16x8*)(w1hp + 128 + k0);
        bf16x8 bl1 = *(const bf16x8*)(w1lp + 128 + k0);
        #pragma unroll
        for (int st = 0; st < 4; ++st) {
            bf16x8 ah = *(const bf16x8*)(sAh + (16 * st + l16) * 136 + k0);
            bf16x8 al = *(const bf16x8*)(sAl + (16 * st + l16) * 136 + k0);
            acc[st][0] = __builtin_amdgcn_mfma_f32_16x16x32_bf16(ah, bh0, acc[st][0], 0, 0, 0);
            acc[st][0] = __builtin_amdgcn_mfma_f32_16x16x32_bf16(al, bh0, acc[st][0], 0, 0, 0);
            acc[st][0] = __builtin_amdgcn_mfma_f32_16x16x32_bf16(ah, bl0, acc[st][0], 0, 0, 0);
            acc[st][1] = __builtin_amdgcn_mfma_f32_16x16x32_bf16(ah, bh1, acc[st][1], 0, 0, 0);
            acc[st][1] = __builtin_amdgcn_mfma_f32_16x16x32_bf16(al, bh1, acc[st][1], 0, 0, 0);
            acc[st][1] = __builtin_amdgcn_mfma_f32_16x16x32_bf16(ah, bl1, acc[st][1], 0, 0, 0);
        }
    }

    const float b1v = b1[n];
    #pragma unroll
    for (int st = 0; st < 4; ++st) {
        #pragma unroll
        for (int r = 0; r < 4; ++r) {
            const int node = node0 + 16 * st + quad * 4 + r;
            if (node < NN) {
                hrp[(size_t)node * 64 + n] = acc[st][0][r] + b1v;
                hsp[(size_t)node * 64 + n] = acc[st][1][r];
            }
        }
    }
}

// standalone node_w1 (layer-2 mean mode)
__global__ __launch_bounds__(256) void node_w1_kernel(
    const float* __restrict__ src, const uint32_t* __restrict__ row_off,
    const float* __restrict__ b1,
    float* __restrict__ hrp, float* __restrict__ hsp, int layer)
{
    node_w1_body(src, row_off, b1, hrp, hsp, layer, blockIdx.x);
}

// ---------------------------------------------------------------------------
// mid_kernel: blocks [0,nbn) = node_w1 layer-0; rest = rank-scatter.
// ---------------------------------------------------------------------------
__global__ __launch_bounds__(256) void mid_kernel(
    const float* __restrict__ x, const float* __restrict__ b1a,
    float* __restrict__ hrp, float* __restrict__ hsp,
    const int* __restrict__ rcv, const int* __restrict__ snd,
    const uint32_t* __restrict__ row_off, uint32_t* __restrict__ cursor,
    int2* __restrict__ srt, int nbn)
{
    if ((int)blockIdx.x < nbn) {
        node_w1_body(x, (const uint32_t*)nullptr, b1a, hrp, hsp, 0, blockIdx.x);
    } else {
        int e = (blockIdx.x - nbn) * 256 + threadIdx.x;
        if (e < NE) {
            int r = rcv[e];
            uint32_t k = atomicAdd(cursor + r, 1u);
            srt[row_off[r] + k] = make_int2(r, snd[e]);
        }
    }
}

// ---------------------------------------------------------------------------
// edge_acc_kernel: NODE-CENTRIC edge phase ONLY (lean: no GEMM1/tail fused,
// so the live set fits the (512,4) 128-VGPR cap without spill — r5/r6's
// failure was the fused kernel's union-of-phases register demand).
// Block owns 64 receivers + their sorted edge range; 8 waves x 16 edges/iter.
// Segment sums in sAcc[64][129] (pad->different banks per quad-row),
// suffix-sum epilogue + predicated ds_adds; final flush = PLAIN STORES to seg
// (block-exclusive rows -> zero global atomics; r2's 0.6TB/s atomic bound
// eliminated). LDS 65.8KB -> 2 blocks (16 waves)/CU at <=128 VGPR.
// ---------------------------------------------------------------------------
__global__ __launch_bounds__(512, 4) void edge_acc_kernel(
    const float* __restrict__ hrpI, const float* __restrict__ hspI,
    const int2* __restrict__ srt, const uint32_t* __restrict__ row_off,
    const float* __restrict__ b2, int layer, float* __restrict__ seg)
{
    __shared__ float sAcc[64][129];                    // 33024 B
    __shared__ __align__(16) __bf16 sWh[128 * 64];     // 16384 B
    __shared__ __align__(16) __bf16 sWl[128 * 64];     // 16384 B

    const int t = threadIdx.x;
    const int w = t >> 6, lane = t & 63, quad = lane >> 4, l16 = lane & 15;
    const int node0 = blockIdx.x * 64;

    // ---- zero sAcc ---------------------------------------------------------
    {
        float* p = &sAcc[0][0];
        for (int i = t; i < 64 * 129; i += 512) p[i] = 0.f;
    }

    // ---- stage W2 planes, swizzled (chunk c of row r at slot c^(r&7)) ------
    {
        const int r = t >> 2, part = t & 3;
        const __bf16* sh = g_w2h[layer] + r * 64;
        const __bf16* sl = g_w2l[layer] + r * 64;
        __bf16* dh = sWh + r * 64;
        __bf16* dl = sWl + r * 64;
        const int rs = r & 7;
        #pragma unroll
        for (int i = 0; i < 2; ++i) {
            const int c = part * 2 + i;
            const int cs = c ^ rs;
            *(bf16x8*)(dh + cs * 8) = *(const bf16x8*)(sh + 8 * c);
            *(bf16x8*)(dl + cs * 8) = *(const bf16x8*)(sl + 8 * c);
        }
    }

    float b2v[8];
    #pragma unroll
    for (int ct = 0; ct < 8; ++ct) b2v[ct] = b2[16 * ct + l16];

    const int e0 = (int)row_off[node0];
    const int e1 = (int)row_off[(node0 + 64 < NN) ? (node0 + 64) : NN];

    __syncthreads();   // sAcc zeroed + weights staged

    // ---- edge loop: wave w handles ONE 16-edge strip/iter, 8 waves->128 ----
    for (int base = e0 + w * 16; base < e1; base += 128) {
        const int iA = base + l16;
        const bool vA = iA < e1;
        const int2 rsA = srt[vA ? iA : e1 - 1];
        const int rlA = vA ? (rsA.x - node0) : -1;   // local receiver or -1

        const float* hpA = hrpI + (size_t)rsA.x * 64 + quad * 8;
        const float* spA = hspI + (size_t)rsA.y * 64 + quad * 8;

        f32x4 ga0[4], gb0[4];
        ga0[0] = *(const f32x4*)(hpA);      ga0[1] = *(const f32x4*)(hpA + 4);
        ga0[2] = *(const f32x4*)(hpA + 32); ga0[3] = *(const f32x4*)(hpA + 36);
        gb0[0] = *(const f32x4*)(spA);      gb0[1] = *(const f32x4*)(spA + 4);
        gb0[2] = *(const f32x4*)(spA + 32); gb0[3] = *(const f32x4*)(spA + 36);

        // ---- per-quad receivers + branch-free run structure ----------------
        const int rA0 = __shfl(rlA, quad * 4 + 0, 16);
        const int rA1 = __shfl(rlA, quad * 4 + 1, 16);
        const int rA2 = __shfl(rlA, quad * 4 + 2, 16);
        const int rA3 = __shfl(rlA, quad * 4 + 3, 16);

        const float cA01 = (rA1 == rA0) ? 1.f : 0.f;
        const float cA12 = (rA2 == rA1) ? 1.f : 0.f;
        const float cA23 = (rA3 == rA2) ? 1.f : 0.f;
        const bool hA0 = (rA0 >= 0);
        const bool hA1 = (rA1 != rA0) && (rA1 >= 0);
        const bool hA2 = (rA2 != rA1) && (rA2 >= 0);
        const bool hA3 = (rA3 != rA2) && (rA3 >= 0);
        const float mA0 = (rA0 >= 0) ? 1.f : 0.f;
        const float mA1 = (rA1 >= 0) ? 1.f : 0.f;
        const float mA2 = (rA2 >= 0) ? 1.f : 0.f;
        const float mA3 = (rA3 >= 0) ? 1.f : 0.f;

        // ---- pack A-fragments: h = relu(hrp+hsp), split hi/lo --------------
        bf16x8 ahA[2], alA[2];
        #pragma unroll
        for (int s = 0; s < 2; ++s) {
            #pragma unroll
            for (int hh = 0; hh < 2; ++hh) {
                f32x4 av = ga0[s * 2 + hh], bv = gb0[s * 2 + hh];
                #pragma unroll
                for (int j = 0; j < 4; ++j) {
                    float fA = fmaxf(av[j] + bv[j], 0.f);
                    __bf16 h, l;
                    split1(fA, h, l); ahA[s][hh * 4 + j] = h; alA[s][hh * 4 + j] = l;
                }
            }
        }

        #pragma unroll
        for (int ct = 0; ct < 8; ++ct) {
            const int r = 16 * ct + l16;
            const int rs = r & 7;
            f32x4 accA = {};
            __builtin_amdgcn_s_setprio(1);
            #pragma unroll
            for (int s = 0; s < 2; ++s) {
                const int cs = (s * 4 + quad) ^ rs;
                bf16x8 bh = *(const bf16x8*)(sWh + r * 64 + cs * 8);
                bf16x8 bl = *(const bf16x8*)(sWl + r * 64 + cs * 8);
                accA = __builtin_amdgcn_mfma_f32_16x16x32_bf16(ahA[s], bh, accA, 0, 0, 0);
                accA = __builtin_amdgcn_mfma_f32_16x16x32_bf16(alA[s], bh, accA, 0, 0, 0);
                accA = __builtin_amdgcn_mfma_f32_16x16x32_bf16(ahA[s], bl, accA, 0, 0, 0);
            }
            __builtin_amdgcn_s_setprio(0);
            const float bv = b2v[ct];
            const float v0 = fmaxf(accA[0] + bv, 0.f) * mA0;
            const float v1 = fmaxf(accA[1] + bv, 0.f) * mA1;
            const float v2 = fmaxf(accA[2] + bv, 0.f) * mA2;
            const float v3 = fmaxf(accA[3] + bv, 0.f) * mA3;
            const float t3 = v3;
            const float t2 = fmaf(cA23, t3, v2);
            const float t1 = fmaf(cA12, t2, v1);
            const float t0 = fmaf(cA01, t1, v0);
            if (hA0) atomicAdd(&sAcc[rA0][r], t0);
            if (hA1) atomicAdd(&sAcc[rA1][r], t1);
            if (hA2) atomicAdd(&sAcc[rA2][r], t2);
            if (hA3) atomicAdd(&sAcc[rA3][r], t3);
        }
    }

    __syncthreads();   // sAcc complete

    // ---- flush: plain stores (block-exclusive seg rows) --------------------
    {
        const int r = t >> 3, c0 = (t & 7) * 16;
        const int node = node0 + r;
        if (node < NN) {
            float* dst = seg + (size_t)node * 128 + c0;
            #pragma unroll
            for (int i = 0; i < 4; ++i)
                *(f32x4*)(dst + 4 * i) = *(const f32x4*)(&sAcc[r][c0 + 4 * i]);
        }
    }
}

// ---------------------------------------------------------------------------
// tail_kernel: per node: m = seg/cnt ; out = relu(m @ Wd1 + bd1) @ Wd2 + bd2
// ---------------------------------------------------------------------------
__global__ __launch_bounds__(256) void tail_kernel(
    const float* __restrict__ seg, const uint32_t* __restrict__ row_off,
    const float* __restrict__ bd1, const float* __restrict__ Wd2,
    const float* __restrict__ bd2, float* __restrict__ out)
{
    __shared__ __align__(16) __bf16 sAh[64 * 136];
    __shared__ __align__(16) __bf16 sAl[64 * 136];
    __shared__ float sOut[64];
    const int t = threadIdx.x;
    const int w = t >> 6, lane = t & 63, quad = lane >> 4, l16 = lane & 15;
    const int node0 = blockIdx.x * 64;

    if (t < 64) sOut[t] = 0.f;

    {
        const int r = t >> 2, kq = (t & 3) * 32;
        const int node = node0 + r;
        f32x4 v[8];
        if (node < NN) {
            uint32_t c = row_off[node + 1] - row_off[node];
            float inv = (c > 0u) ? 1.0f / (float)c : 0.f;
            const float* p = seg + (size_t)node * 128 + kq;
            #pragma unroll
            for (int i = 0; i < 8; ++i) v[i] = *(const f32x4*)(p + 4 * i) * inv;
        } else {
            #pragma unroll
            for (int i = 0; i < 8; ++i) v[i] = (f32x4){0.f, 0.f, 0.f, 0.f};
        }
        bf16x8 hb[4], lb[4];
        #pragma unroll
        for (int i = 0; i < 8; ++i) {
            #pragma unroll
            for (int j = 0; j < 4; ++j) {
                __bf16 h, l; split1(v[i][j], h, l);
                hb[i >> 1][(i & 1) * 4 + j] = h;
                lb[i >> 1][(i & 1) * 4 + j] = l;
            }
        }
        __bf16* dh = sAh + r * 136 + kq;
        __bf16* dl = sAl + r * 136 + kq;
        #pragma unroll
        for (int i = 0; i < 4; ++i) {
            *(bf16x8*)(dh + 8 * i) = hb[i];
            *(bf16x8*)(dl + 8 * i) = lb[i];
        }
    }
    __syncthreads();

    const int n = 16 * w + l16;
    const __bf16* bhp = g_wd1h + n * 128;
    const __bf16* blp = g_wd1l + n * 128;
    f32x4 acc[4] = {};
    #pragma unroll
    for (int kq = 0; kq < 4; ++kq) {
        const int k0 = kq * 32 + quad * 8;
        bf16x8 bh = *(const bf16x8*)(bhp + k0);
        bf16x8 bl = *(const bf16x8*)(blp + k0);
        #pragma unroll
        for (int st = 0; st < 4; ++st) {
            bf16x8 ah = *(const bf16x8*)(sAh + (16 * st + l16) * 136 + k0);
            bf16x8 al = *(const bf16x8*)(sAl + (16 * st + l16) * 136 + k0);
            acc[st] = __builtin_amdgcn_mfma_f32_16x16x32_bf16(ah, bh, acc[st], 0, 0, 0);
            acc[st] = __builtin_amdgcn_mfma_f32_16x16x32_bf16(al, bh, acc[st], 0, 0, 0);
            acc[st] = __builtin_amdgcn_mfma_f32_16x16x32_bf16(ah, bl, acc[st], 0, 0, 0);
        }
    }

    const float bd1v = bd1[n];
    const float wd2v = Wd2[n];
    #pragma unroll
    for (int st = 0; st < 4; ++st) {
        #pragma unroll
        for (int r = 0; r < 4; ++r) {
            float p = fmaxf(acc[st][r] + bd1v, 0.f) * wd2v;
            p += __shfl_xor(p, 1, 16);
            p += __shfl_xor(p, 2, 16);
            p += __shfl_xor(p, 4, 16);
            p += __shfl_xor(p, 8, 16);
            if (l16 == 0) atomicAdd(&sOut[16 * st + quad * 4 + r], p);
        }
    }
    __syncthreads();
    if (t < 64) {
        const int node = node0 + t;
        if (node < NN) out[node] = sOut[t] + bd2[0];
    }
}

// ---------------------------------------------------------------------------
extern "C" void kernel_launch(void* const* d_in, const int* in_sizes, int n_in,
                              void* d_out, int out_size, void* d_ws, size_t ws_size,
                              hipStream_t stream) {
    const float* x   = (const float*)d_in[0];
    const int*   snd = (const int*)  d_in[1];
    const int*   rcv = (const int*)  d_in[2];
    const float* W1a = (const float*)d_in[3];
    const float* b1a = (const float*)d_in[4];
    const float* W2a = (const float*)d_in[5];
    const float* b2a = (const float*)d_in[6];
    const float* W1b = (const float*)d_in[7];
    const float* b1b = (const float*)d_in[8];
    const float* W2b = (const float*)d_in[9];
    const float* b2b = (const float*)d_in[10];
    const float* Wd1 = (const float*)d_in[11];
    const float* bd1 = (const float*)d_in[12];
    const float* Wd2 = (const float*)d_in[13];
    const float* bd2 = (const float*)d_in[14];
    float* out = (float*)d_out;

    // ws layout: seg [NN*128 f32] | hist [NN] | cursor [NN] | row_off [NN+1] |
    //            pre [NN] | bsum [256] | pad [1] | srt [NE int2] | hrp | hsp
    float*    seg     = (float*)d_ws;
    uint32_t* hist    = (uint32_t*)(seg + (size_t)NN * 128);
    uint32_t* cursor  = hist + NN;
    uint32_t* row_off = cursor + NN;
    uint32_t* pre     = row_off + (NN + 1);
    uint32_t* bsum    = pre + NN;
    int2*     srt     = (int2*)(bsum + 256 + 1);   // +1 pad -> 8B aligned
    float*    hrp     = (float*)(srt + NE);
    float*    hsp     = hrp + (size_t)NN * 64;

    hipMemsetAsync(hist, 0, 2 * NN * sizeof(uint32_t), stream);   // hist+cursor

    const int nb  = (NN + 255) / 256;   // 196
    const int nbn = (NN + 63) / 64;     // 782
    const int neb = (NE + 255) / 256;   // 3125

    hipLaunchKernelGGL(pre_kernel, dim3(224 + neb), dim3(256), 0, stream,
                       W1a, W2a, W1b, W2b, Wd1, rcv, hist);
    hipLaunchKernelGGL(scan1_kernel, dim3(nb), dim3(256), 0, stream, hist, pre, bsum);
    hipLaunchKernelGGL(scan23_kernel, dim3(nb), dim3(256), 0, stream, pre, bsum, row_off);
    hipLaunchKernelGGL(mid_kernel, dim3(nbn + neb), dim3(256), 0, stream,
                       x, b1a, hrp, hsp, rcv, snd, row_off, cursor, srt, nbn);

    // layer-1 edges -> seg (plain-store flush, no global atomics)
    hipLaunchKernelGGL(edge_acc_kernel, dim3(nbn), dim3(512), 0, stream,
                       hrp, hsp, srt, row_off, b2a, 0, seg);
    // layer-2 node half-products (mean via row_off; overwrites hrp/hsp)
    hipLaunchKernelGGL(node_w1_kernel, dim3(nbn), dim3(256), 0, stream,
                       seg, row_off, b1b, hrp, hsp, 1);
    // layer-2 edges -> seg
    hipLaunchKernelGGL(edge_acc_kernel, dim3(nbn), dim3(512), 0, stream,
                       hrp, hsp, srt, row_off, b2b, 1, seg);
    // dense tail
    hipLaunchKernelGGL(tail_kernel, dim3(nbn), dim3(256), 0, stream,
                       seg, row_off, bd1, Wd2, bd2, out);
}

// Round 8
// 650.072 us; speedup vs baseline: 1.0850x; 1.0850x over previous
//
#include <hip/hip_runtime.h>
#include <hip/hip_bf16.h>
#include <cstdint>
#include <cstddef>

#define NN 50000
#define NE 800000

typedef __bf16 bf16x8 __attribute__((ext_vector_type(8)));
typedef float  f32x4  __attribute__((ext_vector_type(4)));

// Pre-split, pre-transposed weights (hi/lo bf16 planes).
// W1t: [n][k] n<64,k<256 ; W2t: [n][k] n<128,k<64 ; Wd1t: [n][k] n<64,k<128.
__device__ __bf16 g_w1h[2][64 * 256];
__device__ __bf16 g_w1l[2][64 * 256];
__device__ __bf16 g_w2h[2][128 * 64];
__device__ __bf16 g_w2l[2][128 * 64];
__device__ __bf16 g_wd1h[64 * 128];
__device__ __bf16 g_wd1l[64 * 128];

__device__ __forceinline__ void split1(float v, __bf16& h, __bf16& l) {
    h = (__bf16)v;
    l = (__bf16)(v - (float)h);
}

// ---------------------------------------------------------------------------
// pre_kernel: blocks [0,224) split weights; blocks [224,224+3125) histogram
// ---------------------------------------------------------------------------
__global__ __launch_bounds__(256) void pre_kernel(
    const float* __restrict__ W1a, const float* __restrict__ W2a,
    const float* __restrict__ W1b, const float* __restrict__ W2b,
    const float* __restrict__ Wd1,
    const int* __restrict__ rcv, uint32_t* __restrict__ hist)
{
    const int b = blockIdx.x, t = threadIdx.x;
    if (b < 224) {
        int tid = b * 256 + t;
        if (tid < 16384) {                 // W1a [256][64] -> [64][256]
            int k = tid >> 6, n = tid & 63;
            __bf16 h, l; split1(W1a[tid], h, l);
            g_w1h[0][n * 256 + k] = h; g_w1l[0][n * 256 + k] = l;
        } else if (tid < 24576) {          // W2a [64][128] -> [128][64]
            int i = tid - 16384; int k = i >> 7, n = i & 127;
            __bf16 h, l; split1(W2a[i], h, l);
            g_w2h[0][n * 64 + k] = h; g_w2l[0][n * 64 + k] = l;
        } else if (tid < 40960) {          // W1b
            int i = tid - 24576; int k = i >> 6, n = i & 63;
            __bf16 h, l; split1(W1b[i], h, l);
            g_w1h[1][n * 256 + k] = h; g_w1l[1][n * 256 + k] = l;
        } else if (tid < 49152) {          // W2b
            int i = tid - 40960; int k = i >> 7, n = i & 127;
            __bf16 h, l; split1(W2b[i], h, l);
            g_w2h[1][n * 64 + k] = h; g_w2l[1][n * 64 + k] = l;
        } else if (tid < 57344) {          // Wd1 [128][64] -> [64][128]
            int i = tid - 49152; int k = i >> 6, n = i & 63;
            __bf16 h, l; split1(Wd1[i], h, l);
            g_wd1h[n * 128 + k] = h; g_wd1l[n * 128 + k] = l;
        }
    } else {
        int e = (b - 224) * 256 + t;
        if (e < NE) atomicAdd(hist + rcv[e], 1u);
    }
}

// ---------------------------------------------------------------------------
// counting-sort scan (exact counts)
// ---------------------------------------------------------------------------
__global__ void scan1_kernel(const uint32_t* __restrict__ hist,
                             uint32_t* __restrict__ pre, uint32_t* __restrict__ bsum) {
    __shared__ uint32_t s[256];
    int t = threadIdx.x;
    int i = blockIdx.x * 256 + t;
    uint32_t v = (i < NN) ? hist[i] : 0u;
    s[t] = v; __syncthreads();
    #pragma unroll
    for (int off = 1; off < 256; off <<= 1) {
        uint32_t tv = (t >= off) ? s[t - off] : 0u;
        __syncthreads();
        s[t] += tv; __syncthreads();
    }
    if (i < NN) pre[i] = s[t] - v;
    if (t == 255) bsum[blockIdx.x] = s[255];
}

__global__ void scan23_kernel(const uint32_t* __restrict__ pre,
                              const uint32_t* __restrict__ bsum,
                              uint32_t* __restrict__ row_off) {
    __shared__ uint32_t s[256];
    const int b = blockIdx.x, t = threadIdx.x;
    uint32_t v = (t < b) ? bsum[t] : 0u;     // b <= 195 < 256
    s[t] = v; __syncthreads();
    #pragma unroll
    for (int off = 128; off > 0; off >>= 1) {
        if (t < off) s[t] += s[t + off];
        __syncthreads();
    }
    const uint32_t base = s[0];
    int i = b * 256 + t;
    if (i < NN) row_off[i] = pre[i] + base;
    if (i == 0) row_off[NN] = NE;
}

// ---------------------------------------------------------------------------
// node_w1_body: per-node half-products of GEMM1.
//   hrp[n] = src[n] @ W1_top + b1 ; hsp[n] = src[n] @ W1_bot
// mean-mode (row_off != null): scale src by 1/cnt (cnt = row_off diff).
// ---------------------------------------------------------------------------
__device__ __forceinline__ void node_w1_body(
    const float* __restrict__ src, const uint32_t* __restrict__ row_off,
    const float* __restrict__ b1,
    float* __restrict__ hrp, float* __restrict__ hsp, int layer, int blk)
{
    __shared__ __align__(16) __bf16 sAh[64 * 136];
    __shared__ __align__(16) __bf16 sAl[64 * 136];
    const int t = threadIdx.x;
    const int w = t >> 6, lane = t & 63, quad = lane >> 4, l16 = lane & 15;
    const int node0 = blk * 64;

    {
        const int r = t >> 2, kq = (t & 3) * 32;
        const int node = node0 + r;
        f32x4 v[8];
        if (node < NN) {
            const float* p = src + (size_t)node * 128 + kq;
            #pragma unroll
            for (int i = 0; i < 8; ++i) v[i] = *(const f32x4*)(p + 4 * i);
            if (row_off) {
                uint32_t c = row_off[node + 1] - row_off[node];
                float inv = (c > 0u) ? 1.0f / (float)c : 0.f;
                #pragma unroll
                for (int i = 0; i < 8; ++i) v[i] = v[i] * inv;
            }
        } else {
            #pragma unroll
            for (int i = 0; i < 8; ++i) v[i] = (f32x4){0.f, 0.f, 0.f, 0.f};
        }
        bf16x8 hb[4], lb[4];
        #pragma unroll
        for (int i = 0; i < 8; ++i) {
            #pragma unroll
            for (int j = 0; j < 4; ++j) {
                __bf16 h, l; split1(v[i][j], h, l);
                hb[i >> 1][(i & 1) * 4 + j] = h;
                lb[i >> 1][(i & 1) * 4 + j] = l;
            }
        }
        __bf16* dh = sAh + r * 136 + kq;
        __bf16* dl = sAl + r * 136 + kq;
        #pragma unroll
        for (int i = 0; i < 4; ++i) {
            *(bf16x8*)(dh + 8 * i) = hb[i];
            *(bf16x8*)(dl + 8 * i) = lb[i];
        }
    }
    __syncthreads();

    const int n = 16 * w + l16;
    const __bf16* w1hp = g_w1h[layer] + n * 256;
    const __bf16* w1lp = g_w1l[layer] + n * 256;
    f32x4 acc[4][2] = {};
    #pragma unroll
    for (int kq = 0; kq < 4; ++kq) {
        const int k0 = kq * 32 + quad * 8;
        bf16x8 bh0 = *(const bf16x8*)(w1hp + k0);
        bf16x8 bl0 = *(const bf16x8*)(w1lp + k0);
        bf16x8 bh1 = *(const bf16x8*)(w1hp + 128 + k0);
        bf16x8 bl1 = *(const bf16x8*)(w1lp + 128 + k0);
        #pragma unroll
        for (int st = 0; st < 4; ++st) {
            bf16x8 ah = *(const bf16x8*)(sAh + (16 * st + l16) * 136 + k0);
            bf16x8 al = *(const bf16x8*)(sAl + (16 * st + l16) * 136 + k0);
            acc[st][0] = __builtin_amdgcn_mfma_f32_16x16x32_bf16(ah, bh0, acc[st][0], 0, 0, 0);
            acc[st][0] = __builtin_amdgcn_mfma_f32_16x16x32_bf16(al, bh0, acc[st][0], 0, 0, 0);
            acc[st][0] = __builtin_amdgcn_mfma_f32_16x16x32_bf16(ah, bl0, acc[st][0], 0, 0, 0);
            acc[st][1] = __builtin_amdgcn_mfma_f32_16x16x32_bf16(ah, bh1, acc[st][1], 0, 0, 0);
            acc[st][1] = __builtin_amdgcn_mfma_f32_16x16x32_bf16(al, bh1, acc[st][1], 0, 0, 0);
            acc[st][1] = __builtin_amdgcn_mfma_f32_16x16x32_bf16(ah, bl1, acc[st][1], 0, 0, 0);
        }
    }

    const float b1v = b1[n];
    #pragma unroll
    for (int st = 0; st < 4; ++st) {
        #pragma unroll
        for (int r = 0; r < 4; ++r) {
            const int node = node0 + 16 * st + quad * 4 + r;
            if (node < NN) {
                hrp[(size_t)node * 64 + n] = acc[st][0][r] + b1v;
                hsp[(size_t)node * 64 + n] = acc[st][1][r];
            }
        }
    }
}

// standalone node_w1 (layer-2 mean mode)
__global__ __launch_bounds__(256) void node_w1_kernel(
    const float* __restrict__ src, const uint32_t* __restrict__ row_off,
    const float* __restrict__ b1,
    float* __restrict__ hrp, float* __restrict__ hsp, int layer)
{
    node_w1_body(src, row_off, b1, hrp, hsp, layer, blockIdx.x);
}

// ---------------------------------------------------------------------------
// mid_kernel: blocks [0,nbn) = node_w1 layer-0; rest = rank-scatter.
// ---------------------------------------------------------------------------
__global__ __launch_bounds__(256) void mid_kernel(
    const float* __restrict__ x, const float* __restrict__ b1a,
    float* __restrict__ hrp, float* __restrict__ hsp,
    const int* __restrict__ rcv, const int* __restrict__ snd,
    const uint32_t* __restrict__ row_off, uint32_t* __restrict__ cursor,
    int2* __restrict__ srt, int nbn)
{
    if ((int)blockIdx.x < nbn) {
        node_w1_body(x, (const uint32_t*)nullptr, b1a, hrp, hsp, 0, blockIdx.x);
    } else {
        int e = (blockIdx.x - nbn) * 256 + threadIdx.x;
        if (e < NE) {
            int r = rcv[e];
            uint32_t k = atomicAdd(cursor + r, 1u);
            srt[row_off[r] + k] = make_int2(r, snd[e]);
        }
    }
}

// ---------------------------------------------------------------------------
// edge_acc_kernel: NODE-CENTRIC edge phase, NATURAL register allocation.
// r5/r6/r7 lesson: the two-arg __launch_bounds__ on this toolchain is
// honored as min-BLOCKS/CU (CUDA semantics): (512,4) -> 32 waves/CU ->
// 64-VGPR cap -> spill (VGPR=64, WRITE 112MB observed). Plain (512) lets
// the ~100-reg live set allocate naturally; <=128 VGPR -> 2 blocks
// (16 waves)/CU with 65.8KB LDS.
// Block owns 64 receivers + their sorted edge range; 8 waves x 16 edges/iter.
// Segment sums in sAcc[64][129]; suffix-sum epilogue + predicated ds_adds;
// flush = plain stores to seg (block-exclusive rows, zero global atomics).
// ---------------------------------------------------------------------------
__global__ __launch_bounds__(512) void edge_acc_kernel(
    const float* __restrict__ hrpI, const float* __restrict__ hspI,
    const int2* __restrict__ srt, const uint32_t* __restrict__ row_off,
    const float* __restrict__ b2, int layer, float* __restrict__ seg)
{
    __shared__ float sAcc[64][129];                    // 33024 B
    __shared__ __align__(16) __bf16 sWh[128 * 64];     // 16384 B
    __shared__ __align__(16) __bf16 sWl[128 * 64];     // 16384 B

    const int t = threadIdx.x;
    const int w = t >> 6, lane = t & 63, quad = lane >> 4, l16 = lane & 15;
    const int node0 = blockIdx.x * 64;

    // ---- zero sAcc ---------------------------------------------------------
    {
        float* p = &sAcc[0][0];
        for (int i = t; i < 64 * 129; i += 512) p[i] = 0.f;
    }

    // ---- stage W2 planes, swizzled (chunk c of row r at slot c^(r&7)) ------
    {
        const int r = t >> 2, part = t & 3;
        const __bf16* sh = g_w2h[layer] + r * 64;
        const __bf16* sl = g_w2l[layer] + r * 64;
        __bf16* dh = sWh + r * 64;
        __bf16* dl = sWl + r * 64;
        const int rs = r & 7;
        #pragma unroll
        for (int i = 0; i < 2; ++i) {
            const int c = part * 2 + i;
            const int cs = c ^ rs;
            *(bf16x8*)(dh + cs * 8) = *(const bf16x8*)(sh + 8 * c);
            *(bf16x8*)(dl + cs * 8) = *(const bf16x8*)(sl + 8 * c);
        }
    }

    float b2v[8];
    #pragma unroll
    for (int ct = 0; ct < 8; ++ct) b2v[ct] = b2[16 * ct + l16];

    const int e0 = (int)row_off[node0];
    const int e1 = (int)row_off[(node0 + 64 < NN) ? (node0 + 64) : NN];

    __syncthreads();   // sAcc zeroed + weights staged

    // ---- edge loop: wave w handles ONE 16-edge strip/iter, 8 waves->128 ----
    for (int base = e0 + w * 16; base < e1; base += 128) {
        const int iA = base + l16;
        const bool vA = iA < e1;
        const int2 rsA = srt[vA ? iA : e1 - 1];
        const int rlA = vA ? (rsA.x - node0) : -1;   // local receiver or -1

        const float* hpA = hrpI + (size_t)rsA.x * 64 + quad * 8;
        const float* spA = hspI + (size_t)rsA.y * 64 + quad * 8;

        f32x4 ga0[4], gb0[4];
        ga0[0] = *(const f32x4*)(hpA);      ga0[1] = *(const f32x4*)(hpA + 4);
        ga0[2] = *(const f32x4*)(hpA + 32); ga0[3] = *(const f32x4*)(hpA + 36);
        gb0[0] = *(const f32x4*)(spA);      gb0[1] = *(const f32x4*)(spA + 4);
        gb0[2] = *(const f32x4*)(spA + 32); gb0[3] = *(const f32x4*)(spA + 36);

        // ---- per-quad receivers + branch-free run structure ----------------
        const int rA0 = __shfl(rlA, quad * 4 + 0, 16);
        const int rA1 = __shfl(rlA, quad * 4 + 1, 16);
        const int rA2 = __shfl(rlA, quad * 4 + 2, 16);
        const int rA3 = __shfl(rlA, quad * 4 + 3, 16);

        const float cA01 = (rA1 == rA0) ? 1.f : 0.f;
        const float cA12 = (rA2 == rA1) ? 1.f : 0.f;
        const float cA23 = (rA3 == rA2) ? 1.f : 0.f;
        const bool hA0 = (rA0 >= 0);
        const bool hA1 = (rA1 != rA0) && (rA1 >= 0);
        const bool hA2 = (rA2 != rA1) && (rA2 >= 0);
        const bool hA3 = (rA3 != rA2) && (rA3 >= 0);
        const float mA0 = (rA0 >= 0) ? 1.f : 0.f;
        const float mA1 = (rA1 >= 0) ? 1.f : 0.f;
        const float mA2 = (rA2 >= 0) ? 1.f : 0.f;
        const float mA3 = (rA3 >= 0) ? 1.f : 0.f;

        // ---- pack A-fragments: h = relu(hrp+hsp), split hi/lo --------------
        bf16x8 ahA[2], alA[2];
        #pragma unroll
        for (int s = 0; s < 2; ++s) {
            #pragma unroll
            for (int hh = 0; hh < 2; ++hh) {
                f32x4 av = ga0[s * 2 + hh], bv = gb0[s * 2 + hh];
                #pragma unroll
                for (int j = 0; j < 4; ++j) {
                    float fA = fmaxf(av[j] + bv[j], 0.f);
                    __bf16 h, l;
                    split1(fA, h, l); ahA[s][hh * 4 + j] = h; alA[s][hh * 4 + j] = l;
                }
            }
        }

        #pragma unroll
        for (int ct = 0; ct < 8; ++ct) {
            const int r = 16 * ct + l16;
            const int rs = r & 7;
            f32x4 accA = {};
            __builtin_amdgcn_s_setprio(1);
            #pragma unroll
            for (int s = 0; s < 2; ++s) {
                const int cs = (s * 4 + quad) ^ rs;
                bf16x8 bh = *(const bf16x8*)(sWh + r * 64 + cs * 8);
                bf16x8 bl = *(const bf16x8*)(sWl + r * 64 + cs * 8);
                accA = __builtin_amdgcn_mfma_f32_16x16x32_bf16(ahA[s], bh, accA, 0, 0, 0);
                accA = __builtin_amdgcn_mfma_f32_16x16x32_bf16(alA[s], bh, accA, 0, 0, 0);
                accA = __builtin_amdgcn_mfma_f32_16x16x32_bf16(ahA[s], bl, accA, 0, 0, 0);
            }
            __builtin_amdgcn_s_setprio(0);
            const float bv = b2v[ct];
            const float v0 = fmaxf(accA[0] + bv, 0.f) * mA0;
            const float v1 = fmaxf(accA[1] + bv, 0.f) * mA1;
            const float v2 = fmaxf(accA[2] + bv, 0.f) * mA2;
            const float v3 = fmaxf(accA[3] + bv, 0.f) * mA3;
            const float t3 = v3;
            const float t2 = fmaf(cA23, t3, v2);
            const float t1 = fmaf(cA12, t2, v1);
            const float t0 = fmaf(cA01, t1, v0);
            if (hA0) atomicAdd(&sAcc[rA0][r], t0);
            if (hA1) atomicAdd(&sAcc[rA1][r], t1);
            if (hA2) atomicAdd(&sAcc[rA2][r], t2);
            if (hA3) atomicAdd(&sAcc[rA3][r], t3);
        }
    }

    __syncthreads();   // sAcc complete

    // ---- flush: plain stores (block-exclusive seg rows) --------------------
    {
        const int r = t >> 3, c0 = (t & 7) * 16;
        const int node = node0 + r;
        if (node < NN) {
            float* dst = seg + (size_t)node * 128 + c0;
            #pragma unroll
            for (int i = 0; i < 4; ++i)
                *(f32x4*)(dst + 4 * i) = *(const f32x4*)(&sAcc[r][c0 + 4 * i]);
        }
    }
}

// ---------------------------------------------------------------------------
// tail_kernel: per node: m = seg/cnt ; out = relu(m @ Wd1 + bd1) @ Wd2 + bd2
// ---------------------------------------------------------------------------
__global__ __launch_bounds__(256) void tail_kernel(
    const float* __restrict__ seg, const uint32_t* __restrict__ row_off,
    const float* __restrict__ bd1, const float* __restrict__ Wd2,
    const float* __restrict__ bd2, float* __restrict__ out)
{
    __shared__ __align__(16) __bf16 sAh[64 * 136];
    __shared__ __align__(16) __bf16 sAl[64 * 136];
    __shared__ float sOut[64];
    const int t = threadIdx.x;
    const int w = t >> 6, lane = t & 63, quad = lane >> 4, l16 = lane & 15;
    const int node0 = blockIdx.x * 64;

    if (t < 64) sOut[t] = 0.f;

    {
        const int r = t >> 2, kq = (t & 3) * 32;
        const int node = node0 + r;
        f32x4 v[8];
        if (node < NN) {
            uint32_t c = row_off[node + 1] - row_off[node];
            float inv = (c > 0u) ? 1.0f / (float)c : 0.f;
            const float* p = seg + (size_t)node * 128 + kq;
            #pragma unroll
            for (int i = 0; i < 8; ++i) v[i] = *(const f32x4*)(p + 4 * i) * inv;
        } else {
            #pragma unroll
            for (int i = 0; i < 8; ++i) v[i] = (f32x4){0.f, 0.f, 0.f, 0.f};
        }
        bf16x8 hb[4], lb[4];
        #pragma unroll
        for (int i = 0; i < 8; ++i) {
            #pragma unroll
            for (int j = 0; j < 4; ++j) {
                __bf16 h, l; split1(v[i][j], h, l);
                hb[i >> 1][(i & 1) * 4 + j] = h;
                lb[i >> 1][(i & 1) * 4 + j] = l;
            }
        }
        __bf16* dh = sAh + r * 136 + kq;
        __bf16* dl = sAl + r * 136 + kq;
        #pragma unroll
        for (int i = 0; i < 4; ++i) {
            *(bf16x8*)(dh + 8 * i) = hb[i];
            *(bf16x8*)(dl + 8 * i) = lb[i];
        }
    }
    __syncthreads();

    const int n = 16 * w + l16;
    const __bf16* bhp = g_wd1h + n * 128;
    const __bf16* blp = g_wd1l + n * 128;
    f32x4 acc[4] = {};
    #pragma unroll
    for (int kq = 0; kq < 4; ++kq) {
        const int k0 = kq * 32 + quad * 8;
        bf16x8 bh = *(const bf16x8*)(bhp + k0);
        bf16x8 bl = *(const bf16x8*)(blp + k0);
        #pragma unroll
        for (int st = 0; st < 4; ++st) {
            bf16x8 ah = *(const bf16x8*)(sAh + (16 * st + l16) * 136 + k0);
            bf16x8 al = *(const bf16x8*)(sAl + (16 * st + l16) * 136 + k0);
            acc[st] = __builtin_amdgcn_mfma_f32_16x16x32_bf16(ah, bh, acc[st], 0, 0, 0);
            acc[st] = __builtin_amdgcn_mfma_f32_16x16x32_bf16(al, bh, acc[st], 0, 0, 0);
            acc[st] = __builtin_amdgcn_mfma_f32_16x16x32_bf16(ah, bl, acc[st], 0, 0, 0);
        }
    }

    const float bd1v = bd1[n];
    const float wd2v = Wd2[n];
    #pragma unroll
    for (int st = 0; st < 4; ++st) {
        #pragma unroll
        for (int r = 0; r < 4; ++r) {
            float p = fmaxf(acc[st][r] + bd1v, 0.f) * wd2v;
            p += __shfl_xor(p, 1, 16);
            p += __shfl_xor(p, 2, 16);
            p += __shfl_xor(p, 4, 16);
            p += __shfl_xor(p, 8, 16);
            if (l16 == 0) atomicAdd(&sOut[16 * st + quad * 4 + r], p);
        }
    }
    __syncthreads();
    if (t < 64) {
        const int node = node0 + t;
        if (node < NN) out[node] = sOut[t] + bd2[0];
    }
}

// ---------------------------------------------------------------------------
extern "C" void kernel_launch(void* const* d_in, const int* in_sizes, int n_in,
                              void* d_out, int out_size, void* d_ws, size_t ws_size,
                              hipStream_t stream) {
    const float* x   = (const float*)d_in[0];
    const int*   snd = (const int*)  d_in[1];
    const int*   rcv = (const int*)  d_in[2];
    const float* W1a = (const float*)d_in[3];
    const float* b1a = (const float*)d_in[4];
    const float* W2a = (const float*)d_in[5];
    const float* b2a = (const float*)d_in[6];
    const float* W1b = (const float*)d_in[7];
    const float* b1b = (const float*)d_in[8];
    const float* W2b = (const float*)d_in[9];
    const float* b2b = (const float*)d_in[10];
    const float* Wd1 = (const float*)d_in[11];
    const float* bd1 = (const float*)d_in[12];
    const float* Wd2 = (const float*)d_in[13];
    const float* bd2 = (const float*)d_in[14];
    float* out = (float*)d_out;

    // ws layout: seg [NN*128 f32] | hist [NN] | cursor [NN] | row_off [NN+1] |
    //            pre [NN] | bsum [256] | pad [1] | srt [NE int2] | hrp | hsp
    float*    seg     = (float*)d_ws;
    uint32_t* hist    = (uint32_t*)(seg + (size_t)NN * 128);
    uint32_t* cursor  = hist + NN;
    uint32_t* row_off = cursor + NN;
    uint32_t* pre     = row_off + (NN + 1);
    uint32_t* bsum    = pre + NN;
    int2*     srt     = (int2*)(bsum + 256 + 1);   // +1 pad -> 8B aligned
    float*    hrp     = (float*)(srt + NE);
    float*    hsp     = hrp + (size_t)NN * 64;

    hipMemsetAsync(hist, 0, 2 * NN * sizeof(uint32_t), stream);   // hist+cursor

    const int nb  = (NN + 255) / 256;   // 196
    const int nbn = (NN + 63) / 64;     // 782
    const int neb = (NE + 255) / 256;   // 3125

    hipLaunchKernelGGL(pre_kernel, dim3(224 + neb), dim3(256), 0, stream,
                       W1a, W2a, W1b, W2b, Wd1, rcv, hist);
    hipLaunchKernelGGL(scan1_kernel, dim3(nb), dim3(256), 0, stream, hist, pre, bsum);
    hipLaunchKernelGGL(scan23_kernel, dim3(nb), dim3(256), 0, stream, pre, bsum, row_off);
    hipLaunchKernelGGL(mid_kernel, dim3(nbn + neb), dim3(256), 0, stream,
                       x, b1a, hrp, hsp, rcv, snd, row_off, cursor, srt, nbn);

    // layer-1 edges -> seg (plain-store flush, no global atomics)
    hipLaunchKernelGGL(edge_acc_kernel, dim3(nbn), dim3(512), 0, stream,
                       hrp, hsp, srt, row_off, b2a, 0, seg);
    // layer-2 node half-products (mean via row_off; overwrites hrp/hsp)
    hipLaunchKernelGGL(node_w1_kernel, dim3(nbn), dim3(256), 0, stream,
                       seg, row_off, b1b, hrp, hsp, 1);
    // layer-2 edges -> seg
    hipLaunchKernelGGL(edge_acc_kernel, dim3(nbn), dim3(512), 0, stream,
                       hrp, hsp, srt, row_off, b2b, 1, seg);
    // dense tail
    hipLaunchKernelGGL(tail_kernel, dim3(nbn), dim3(256), 0, stream,
                       seg, row_off, bd1, Wd2, bd2, out);
}